// Round 4
// baseline (7795.546 us; speedup 1.0000x reference)
//
#include <hip/hip_runtime.h>

// ---------------------------------------------------------------------------
// VanillaRNN on MI355X.  B=64, T=512, I=512, H=1024, C=1000.
//
// 256 persistent waves (256 WGs x 64 threads, one wave/CU):
//   wave (g,w): batch group g (rows g*16..+15), columns w*16..+15.
//   Wh + Wx held in VGPRs as MFMA B-fragments (one-time load).
//
// Per-step handoff (no LDS, no __syncthreads, no acquire-invalidate):
//   producer: plain bf16 stores of h_t (R1-proven path) ->
//             ONE RELEASE agent atomic flag store per wave
//             (lowers to s_waitcnt vmcnt(0) + buffer_wbl2 sc1 + wait +
//              store: flushes this wave's h stores L2->L3, invalidates
//              NOTHING -> x/W stay L2-cached).
//   consumer: poll 64 relaxed agent flag loads (sc1, L3-direct) ->
//             h A-fragments via relaxed agent ATOMIC 8-B loads (sc1 ->
//             reads the L3 coherence point; atomics are never hoisted
//             above the data-dependent poll exit).
// Flags poison 0xAAAAAAAA < 0 == "not ready" -> harness re-poison is init.
// Fragment assembly uses __builtin_memcpy (no type-punning UB — the R2/R3
// failure was a TBAA-reordered LDS repack read).
// ---------------------------------------------------------------------------

typedef __bf16 bf16x8 __attribute__((ext_vector_type(8)));
typedef float  f32x4  __attribute__((ext_vector_type(4)));
typedef unsigned long long u64;

#define B_SZ 64
#define T_SZ 512
#define IDIM 512
#define HDIM 1024
#define NCLS 1000

__device__ __forceinline__ float tanh_fast(float v) {
    // tanh(v) = 1 - 2/(exp(2v)+1);  exp(2v) = exp2(v * 2*log2(e))
    float e = __builtin_amdgcn_exp2f(v * 2.885390081777927f);
    return 1.f - 2.f * __builtin_amdgcn_rcpf(e + 1.f);
}

// MFMA 16x16x32 bf16 layouts (m89/m91 verified):
//   A[m = lane&15][k = (lane>>4)*8 + j]
//   B[k = (lane>>4)*8 + j][n = lane&15]
//   D[row = (lane>>4)*4 + r][col = lane&15]

__global__ __launch_bounds__(64, 1)
void rnn_persistent(const float* __restrict__ x,    // (64,512,512)
                    const float* __restrict__ Wx,   // (1024,512)
                    const float* __restrict__ bx,   // (1024)
                    const float* __restrict__ Wh,   // (1024,1024)
                    __bf16* h_hist,                 // (512,64,1024) bf16, ws
                    int* flags)                     // (4*64) per-wave flags, ws
{
    const int g    = blockIdx.x >> 6;   // batch group 0..3 (rows g*16..+15)
    const int w    = blockIdx.x & 63;   // wave-in-group 0..63 (cols w*16..+15)
    const int lane = threadIdx.x;       // 0..63
    const int l15  = lane & 15;
    const int quad = lane >> 4;
    const int nabs = w * 16 + l15;      // this lane's output column

    // ---- one-time: Wx (16 ksteps) + Wh (32 ksteps) B-fragments in VGPRs ----
    bf16x8 wxf[16];
    bf16x8 whf[32];
#pragma unroll
    for (int kk = 0; kk < 16; ++kk) {
        const float4* p = (const float4*)(Wx + (size_t)nabs * IDIM + kk * 32 + quad * 8);
        float4 a = p[0], b = p[1];
        bf16x8 v;
        v[0]=(__bf16)a.x; v[1]=(__bf16)a.y; v[2]=(__bf16)a.z; v[3]=(__bf16)a.w;
        v[4]=(__bf16)b.x; v[5]=(__bf16)b.y; v[6]=(__bf16)b.z; v[7]=(__bf16)b.w;
        wxf[kk] = v;
    }
#pragma unroll
    for (int kk = 0; kk < 32; ++kk) {
        const float4* p = (const float4*)(Wh + (size_t)nabs * HDIM + kk * 32 + quad * 8);
        float4 a = p[0], b = p[1];
        bf16x8 v;
        v[0]=(__bf16)a.x; v[1]=(__bf16)a.y; v[2]=(__bf16)a.z; v[3]=(__bf16)a.w;
        v[4]=(__bf16)b.x; v[5]=(__bf16)b.y; v[6]=(__bf16)b.z; v[7]=(__bf16)b.w;
        whf[kk] = v;
    }
    const float bxv = bx[nabs];

    const float* xrow = x + (size_t)(g * 16 + l15) * T_SZ * IDIM + quad * 8;

    for (int t = 1; t <= T_SZ; ++t) {
        f32x4 acc0 = {0.f, 0.f, 0.f, 0.f};
        f32x4 acc1 = {0.f, 0.f, 0.f, 0.f};

        // ---- xh MFMAs BEFORE the poll (independent of h; hides producers) --
        {
            const float4* xp = (const float4*)(xrow + (size_t)(t - 1) * IDIM);
#pragma unroll
            for (int kk = 0; kk < 16; kk += 2) {
                float4 a = xp[kk * 8], b = xp[kk * 8 + 1];
                bf16x8 v0;
                v0[0]=(__bf16)a.x; v0[1]=(__bf16)a.y; v0[2]=(__bf16)a.z; v0[3]=(__bf16)a.w;
                v0[4]=(__bf16)b.x; v0[5]=(__bf16)b.y; v0[6]=(__bf16)b.z; v0[7]=(__bf16)b.w;
                acc0 = __builtin_amdgcn_mfma_f32_16x16x32_bf16(v0, wxf[kk], acc0, 0, 0, 0);
                float4 a2 = xp[kk * 8 + 8], b2 = xp[kk * 8 + 9];
                bf16x8 v1;
                v1[0]=(__bf16)a2.x; v1[1]=(__bf16)a2.y; v1[2]=(__bf16)a2.z; v1[3]=(__bf16)a2.w;
                v1[4]=(__bf16)b2.x; v1[5]=(__bf16)b2.y; v1[6]=(__bf16)b2.z; v1[7]=(__bf16)b2.w;
                acc1 = __builtin_amdgcn_mfma_f32_16x16x32_bf16(v1, wxf[kk + 1], acc1, 0, 0, 0);
            }
        }

        if (t > 1) {
            // ---- poll the 64 producer-wave flags of my batch group ---------
            const int* fl = flags + g * 64;
            for (;;) {
                int f = __hip_atomic_load(fl + lane, __ATOMIC_RELAXED, __HIP_MEMORY_SCOPE_AGENT);
                if (__all(f >= t - 1)) break;
            }

            // ---- h A-frags: relaxed agent ATOMIC 8-B loads, 4-group pipe ---
            const u64* hq = (const u64*)(h_hist + ((size_t)(t - 2) * B_SZ + g * 16 + l15) * HDIM + quad * 8);
            u64 hb[2][16];
#pragma unroll
            for (int i = 0; i < 8; ++i) {
                hb[0][2 * i]     = __hip_atomic_load(hq + i * 8,     __ATOMIC_RELAXED, __HIP_MEMORY_SCOPE_AGENT);
                hb[0][2 * i + 1] = __hip_atomic_load(hq + i * 8 + 1, __ATOMIC_RELAXED, __HIP_MEMORY_SCOPE_AGENT);
            }
#pragma unroll
            for (int grp = 0; grp < 4; ++grp) {
                if (grp < 3) {
                    const u64* hn = hq + (grp + 1) * 64;   // next 8 kk chunks
#pragma unroll
                    for (int i = 0; i < 8; ++i) {
                        hb[(grp + 1) & 1][2 * i]     = __hip_atomic_load(hn + i * 8,     __ATOMIC_RELAXED, __HIP_MEMORY_SCOPE_AGENT);
                        hb[(grp + 1) & 1][2 * i + 1] = __hip_atomic_load(hn + i * 8 + 1, __ATOMIC_RELAXED, __HIP_MEMORY_SCOPE_AGENT);
                    }
                }
#pragma unroll
                for (int i = 0; i < 8; i += 2) {
                    bf16x8 fa, fb;
                    u64 qa[2] = { hb[grp & 1][2 * i],     hb[grp & 1][2 * i + 1] };
                    u64 qb[2] = { hb[grp & 1][2 * i + 2], hb[grp & 1][2 * i + 3] };
                    __builtin_memcpy(&fa, qa, 16);
                    __builtin_memcpy(&fb, qb, 16);
                    acc0 = __builtin_amdgcn_mfma_f32_16x16x32_bf16(fa, whf[grp * 8 + i],     acc0, 0, 0, 0);
                    acc1 = __builtin_amdgcn_mfma_f32_16x16x32_bf16(fb, whf[grp * 8 + i + 1], acc1, 0, 0, 0);
                }
            }
        }

        // ---- epilogue: tanh + direct bf16 stores (R1-proven path) ----------
        {
            __bf16* hout = h_hist + (size_t)(t - 1) * B_SZ * HDIM;
#pragma unroll
            for (int r = 0; r < 4; ++r) {
                float a = acc0[r] + acc1[r] + bxv;
                hout[(size_t)(g * 16 + quad * 4 + r) * HDIM + nabs] = (__bf16)tanh_fast(a);
            }
        }

        // ---- publish: RELEASE agent flag store (vmcnt drain + wbl2 + store)
        if (lane == 0)
            __hip_atomic_store(flags + g * 64 + w, t,
                               __ATOMIC_RELEASE, __HIP_MEMORY_SCOPE_AGENT);
    }
}

// ---------------------------------------------------------------------------
// logits[b][j] = sum_k hT[b][k] * Wy[j][k] + by[j]   (fp32 compute)
// ---------------------------------------------------------------------------
__global__ __launch_bounds__(256)
void logits_k(const __bf16* __restrict__ hT,   // (64,1024) bf16
              const float* __restrict__ Wy,    // (1000,1024)
              const float* __restrict__ by,    // (1000)
              float* __restrict__ out)         // (64,1000)
{
    const int j = blockIdx.x;
    const int q = threadIdx.x & 3;
    const int b = threadIdx.x >> 2;
    const float*  wr = Wy + (size_t)j * HDIM + q * 256;
    const __bf16* hr = hT + (size_t)b * HDIM + q * 256;
    float s = 0.f;
#pragma unroll 8
    for (int kk = 0; kk < 32; ++kk) {
        bf16x8 h8 = *(const bf16x8*)(hr + kk * 8);
        float4 w0 = *(const float4*)(wr + kk * 8);
        float4 w1 = *(const float4*)(wr + kk * 8 + 4);
        s += w0.x * (float)h8[0] + w0.y * (float)h8[1] + w0.z * (float)h8[2] + w0.w * (float)h8[3]
           + w1.x * (float)h8[4] + w1.y * (float)h8[5] + w1.z * (float)h8[6] + w1.w * (float)h8[7];
    }
    s += __shfl_xor(s, 1);
    s += __shfl_xor(s, 2);
    if (q == 0) out[b * NCLS + j] = s + by[j];
}

extern "C" void kernel_launch(void* const* d_in, const int* in_sizes, int n_in,
                              void* d_out, int out_size, void* d_ws, size_t ws_size,
                              hipStream_t stream) {
    (void)in_sizes; (void)n_in; (void)out_size; (void)ws_size;
    const float* x  = (const float*)d_in[0];
    const float* Wx = (const float*)d_in[1];
    const float* bx = (const float*)d_in[2];
    const float* Wh = (const float*)d_in[3];
    const float* Wy = (const float*)d_in[4];
    const float* by = (const float*)d_in[5];

    __bf16* h_hist = (__bf16*)d_ws;                                   // 64 MB
    int*    flags  = (int*)((char*)d_ws + (size_t)T_SZ * B_SZ * HDIM * 2);

    rnn_persistent<<<dim3(256), dim3(64), 0, stream>>>(x, Wx, bx, Wh, h_hist, flags);

    const __bf16* hT = h_hist + (size_t)(T_SZ - 1) * B_SZ * HDIM;
    logits_k<<<dim3(NCLS), dim3(256), 0, stream>>>(hT, Wy, by, (float*)d_out);
}

// Round 5
// 4848.504 us; speedup vs baseline: 1.6078x; 1.6078x over previous
//
#include <hip/hip_runtime.h>

// ---------------------------------------------------------------------------
// VanillaRNN on MI355X.  B=64, T=512, I=512, H=1024, C=1000.
//
// Phase 1: xh[b,t,:] = x[b,t,:] @ Wx^T + bx   -- parallel MFMA GEMM, bf16 out
//          (fp32 accumulate; bias folded; written to ws).
// Phase 2: ring kernel, 256 persistent waves (256 WGs x 64 thr, 1 wave/CU):
//          wave (g,w) owns batch rows g*16..+15, cols w*16..+15.
//          Wh B-fragments in VGPRs. Per step:
//            poll 64 relaxed agent flags -> h A-frags via relaxed agent
//            ATOMIC 8-B loads (sc1, L3-direct; R4-proven consumer) ->
//            32 MFMAs -> tanh(+xh) -> relaxed agent ATOMIC 2-B stores (sc1,
//            straight to L3 -- NO wbl2, NO L2 flush) ->
//            s_waitcnt vmcnt(0) (asm, memory clobber) -> relaxed flag store.
//          h lives in a DEPTH-4 ring buffer (512 KB, L3-hot). Flag sync
//          proves depth-2 suffices (producer rewriting slot s at step t+4
//          has seen flags >= t+3, i.e. all readers of s at step t+1 done).
// Phase 3: fp32 logits GEMV.
// Flags poison 0xAAAAAAAA < 0 == "not ready" -> harness re-poison is init.
// No LDS anywhere in the hot loops (R2/R3 failure was a TBAA-broken repack).
// ---------------------------------------------------------------------------

typedef __bf16 bf16x8 __attribute__((ext_vector_type(8)));
typedef float  f32x4  __attribute__((ext_vector_type(4)));
typedef unsigned long long u64;

#define B_SZ 64
#define T_SZ 512
#define IDIM 512
#define HDIM 1024
#define NCLS 1000

__device__ __forceinline__ float tanh_fast(float v) {
    // tanh(v) = 1 - 2/(exp(2v)+1);  exp(2v) = exp2(v * 2*log2(e))
    float e = __builtin_amdgcn_exp2f(v * 2.885390081777927f);
    return 1.f - 2.f * __builtin_amdgcn_rcpf(e + 1.f);
}

__device__ __forceinline__ bf16x8 cvt8(float4 a, float4 b) {
    bf16x8 v;
    v[0]=(__bf16)a.x; v[1]=(__bf16)a.y; v[2]=(__bf16)a.z; v[3]=(__bf16)a.w;
    v[4]=(__bf16)b.x; v[5]=(__bf16)b.y; v[6]=(__bf16)b.z; v[7]=(__bf16)b.w;
    return v;
}

// MFMA 16x16x32 bf16 layouts (m89/m91 verified):
//   A[m = lane&15][k = (lane>>4)*8 + j]
//   B[k = (lane>>4)*8 + j][n = lane&15]
//   D[row = (lane>>4)*4 + r][col = lane&15]

// ---------------------------------------------------------------------------
// Phase 1: xh GEMM.  grid 8192 x 256: tile 64 rows (m = b*T+t) x 64 cols.
// ---------------------------------------------------------------------------
__global__ __launch_bounds__(256)
void xh_gemm(const float* __restrict__ x,    // (32768, 512)
             const float* __restrict__ Wx,   // (1024, 512)
             const float* __restrict__ bx,   // (1024)
             __bf16* __restrict__ xh)        // (32768, 1024) bf16
{
    const int m0   = (blockIdx.x >> 4) * 64;
    const int n0   = (blockIdx.x & 15) * 64;
    const int wv   = threadIdx.x >> 6;
    const int lane = threadIdx.x & 63;
    const int l15  = lane & 15;
    const int quad = lane >> 4;
    const int nabs = n0 + wv * 16 + l15;

    bf16x8 wxf[16];
#pragma unroll
    for (int kk = 0; kk < 16; ++kk) {
        const float4* p = (const float4*)(Wx + (size_t)nabs * IDIM + kk * 32 + quad * 8);
        wxf[kk] = cvt8(p[0], p[1]);
    }
    const float bxv = bx[nabs];

    f32x4 acc[4] = {{0,0,0,0},{0,0,0,0},{0,0,0,0},{0,0,0,0}};
#pragma unroll
    for (int kk = 0; kk < 16; ++kk) {
#pragma unroll
        for (int rf = 0; rf < 4; ++rf) {
            const float4* p = (const float4*)(x + (size_t)(m0 + rf * 16 + l15) * IDIM + kk * 32 + quad * 8);
            bf16x8 a = cvt8(p[0], p[1]);
            acc[rf] = __builtin_amdgcn_mfma_f32_16x16x32_bf16(a, wxf[kk], acc[rf], 0, 0, 0);
        }
    }
#pragma unroll
    for (int rf = 0; rf < 4; ++rf)
#pragma unroll
        for (int r = 0; r < 4; ++r)
            xh[(size_t)(m0 + rf * 16 + quad * 4 + r) * HDIM + nabs] = (__bf16)(acc[rf][r] + bxv);
}

// ---------------------------------------------------------------------------
// Phase 2: the ring.  HAS_XH: xh precomputed in ws; else in-ring xh MFMAs.
// ---------------------------------------------------------------------------
template <bool HAS_XH>
__global__ __launch_bounds__(64, 1)
void rnn_ring(const float* __restrict__ x,    // (64,512,512)
              const float* __restrict__ Wx,   // (1024,512)
              const float* __restrict__ bx,   // (1024)
              const float* __restrict__ Wh,   // (1024,1024)
              const __bf16* __restrict__ xh,  // (32768,1024) bf16 (HAS_XH)
              __bf16* h_ring,                 // (4,64,1024) bf16, ws
              int* flags)                     // (4*64) per-wave flags, ws
{
    const int g    = blockIdx.x >> 6;   // batch group 0..3 (rows g*16..+15)
    const int w    = blockIdx.x & 63;   // wave-in-group (cols w*16..+15)
    const int lane = threadIdx.x;
    const int l15  = lane & 15;
    const int quad = lane >> 4;
    const int nabs = w * 16 + l15;

    bf16x8 whf[32];
#pragma unroll
    for (int kk = 0; kk < 32; ++kk) {
        const float4* p = (const float4*)(Wh + (size_t)nabs * HDIM + kk * 32 + quad * 8);
        whf[kk] = cvt8(p[0], p[1]);
    }
    bf16x8 wxf[16];
    float bxv = 0.f;
    if (!HAS_XH) {
#pragma unroll
        for (int kk = 0; kk < 16; ++kk) {
            const float4* p = (const float4*)(Wx + (size_t)nabs * IDIM + kk * 32 + quad * 8);
            wxf[kk] = cvt8(p[0], p[1]);
        }
        bxv = bx[nabs];
    }

    const float* xrow = x + (size_t)(g * 16 + l15) * T_SZ * IDIM + quad * 8;

    for (int t = 1; t <= T_SZ; ++t) {
        f32x4 acc0 = {0.f, 0.f, 0.f, 0.f};
        f32x4 acc1 = {0.f, 0.f, 0.f, 0.f};
        float xhv[4];

        if (HAS_XH) {
            // 4 tiny loads; latency hidden under poll + h-MFMAs
#pragma unroll
            for (int r = 0; r < 4; ++r)
                xhv[r] = (float)xh[((size_t)(g * 16 + quad * 4 + r) * T_SZ + (t - 1)) * HDIM + nabs];
        } else {
            const float4* xp = (const float4*)(xrow + (size_t)(t - 1) * IDIM);
#pragma unroll
            for (int kk = 0; kk < 16; kk += 2) {
                bf16x8 v0 = cvt8(xp[kk * 8], xp[kk * 8 + 1]);
                acc0 = __builtin_amdgcn_mfma_f32_16x16x32_bf16(v0, wxf[kk], acc0, 0, 0, 0);
                bf16x8 v1 = cvt8(xp[kk * 8 + 8], xp[kk * 8 + 9]);
                acc1 = __builtin_amdgcn_mfma_f32_16x16x32_bf16(v1, wxf[kk + 1], acc1, 0, 0, 0);
            }
#pragma unroll
            for (int r = 0; r < 4; ++r) xhv[r] = bxv;
        }

        if (t > 1) {
            // ---- poll the 64 producer-wave flags of my batch group ---------
            const int* fl = flags + g * 64;
            for (;;) {
                int f = __hip_atomic_load(fl + lane, __ATOMIC_RELAXED, __HIP_MEMORY_SCOPE_AGENT);
                if (__all(f >= t - 1)) break;
            }

            // ---- h A-frags: relaxed agent ATOMIC 8-B loads, 4-group pipe ---
            const u64* hq = (const u64*)(h_ring + ((size_t)(((t - 2) & 3)) * B_SZ + g * 16 + l15) * HDIM + quad * 8);
            u64 hb[2][16];
#pragma unroll
            for (int i = 0; i < 8; ++i) {
                hb[0][2 * i]     = __hip_atomic_load(hq + i * 8,     __ATOMIC_RELAXED, __HIP_MEMORY_SCOPE_AGENT);
                hb[0][2 * i + 1] = __hip_atomic_load(hq + i * 8 + 1, __ATOMIC_RELAXED, __HIP_MEMORY_SCOPE_AGENT);
            }
#pragma unroll
            for (int grp = 0; grp < 4; ++grp) {
                if (grp < 3) {
                    const u64* hn = hq + (grp + 1) * 64;
#pragma unroll
                    for (int i = 0; i < 8; ++i) {
                        hb[(grp + 1) & 1][2 * i]     = __hip_atomic_load(hn + i * 8,     __ATOMIC_RELAXED, __HIP_MEMORY_SCOPE_AGENT);
                        hb[(grp + 1) & 1][2 * i + 1] = __hip_atomic_load(hn + i * 8 + 1, __ATOMIC_RELAXED, __HIP_MEMORY_SCOPE_AGENT);
                    }
                }
#pragma unroll
                for (int i = 0; i < 8; i += 2) {
                    bf16x8 fa, fb;
                    u64 qa[2] = { hb[grp & 1][2 * i],     hb[grp & 1][2 * i + 1] };
                    u64 qb[2] = { hb[grp & 1][2 * i + 2], hb[grp & 1][2 * i + 3] };
                    __builtin_memcpy(&fa, qa, 16);
                    __builtin_memcpy(&fb, qb, 16);
                    acc0 = __builtin_amdgcn_mfma_f32_16x16x32_bf16(fa, whf[grp * 8 + i],     acc0, 0, 0, 0);
                    acc1 = __builtin_amdgcn_mfma_f32_16x16x32_bf16(fb, whf[grp * 8 + i + 1], acc1, 0, 0, 0);
                }
            }
        }

        // ---- epilogue: tanh + relaxed agent ATOMIC 2-B stores (sc1 -> L3) --
        {
            __bf16* hout = h_ring + (size_t)((t - 1) & 3) * B_SZ * HDIM;
#pragma unroll
            for (int r = 0; r < 4; ++r) {
                float a = acc0[r] + acc1[r] + xhv[r];
                __bf16 hv = (__bf16)tanh_fast(a);
                unsigned short bits = __builtin_bit_cast(unsigned short, hv);
                unsigned short* dst = (unsigned short*)
                    (hout + (size_t)(g * 16 + quad * 4 + r) * HDIM + nabs);
                __hip_atomic_store(dst, bits, __ATOMIC_RELAXED, __HIP_MEMORY_SCOPE_AGENT);
            }
        }

        // ---- publish: drain sc1 stores to L3, then relaxed flag (no wbl2) --
        __asm__ __volatile__("s_waitcnt vmcnt(0)" ::: "memory");
        if (lane == 0)
            __hip_atomic_store(flags + g * 64 + w, t,
                               __ATOMIC_RELAXED, __HIP_MEMORY_SCOPE_AGENT);
    }
}

// ---------------------------------------------------------------------------
// Phase 3: logits[b][j] = sum_k hT[b][k] * Wy[j][k] + by[j]   (fp32)
// ---------------------------------------------------------------------------
__global__ __launch_bounds__(256)
void logits_k(const __bf16* __restrict__ hT,   // (64,1024) bf16
              const float* __restrict__ Wy,    // (1000,1024)
              const float* __restrict__ by,    // (1000)
              float* __restrict__ out)         // (64,1000)
{
    const int j = blockIdx.x;
    const int q = threadIdx.x & 3;
    const int b = threadIdx.x >> 2;
    const float*  wr = Wy + (size_t)j * HDIM + q * 256;
    const __bf16* hr = hT + (size_t)b * HDIM + q * 256;
    float s = 0.f;
#pragma unroll 8
    for (int kk = 0; kk < 32; ++kk) {
        bf16x8 h8 = *(const bf16x8*)(hr + kk * 8);
        float4 w0 = *(const float4*)(wr + kk * 8);
        float4 w1 = *(const float4*)(wr + kk * 8 + 4);
        s += w0.x * (float)h8[0] + w0.y * (float)h8[1] + w0.z * (float)h8[2] + w0.w * (float)h8[3]
           + w1.x * (float)h8[4] + w1.y * (float)h8[5] + w1.z * (float)h8[6] + w1.w * (float)h8[7];
    }
    s += __shfl_xor(s, 1);
    s += __shfl_xor(s, 2);
    if (q == 0) out[b * NCLS + j] = s + by[j];
}

extern "C" void kernel_launch(void* const* d_in, const int* in_sizes, int n_in,
                              void* d_out, int out_size, void* d_ws, size_t ws_size,
                              hipStream_t stream) {
    (void)in_sizes; (void)n_in; (void)out_size;
    const float* x  = (const float*)d_in[0];
    const float* Wx = (const float*)d_in[1];
    const float* bx = (const float*)d_in[2];
    const float* Wh = (const float*)d_in[3];
    const float* Wy = (const float*)d_in[4];
    const float* by = (const float*)d_in[5];

    const size_t xh_bytes    = (size_t)B_SZ * T_SZ * HDIM * 2;   // 67.1 MB
    const size_t hring_bytes = (size_t)4 * B_SZ * HDIM * 2;      // 512 KB
    const bool   big_ws      = ws_size >= xh_bytes + hring_bytes + 4096;

    if (big_ws) {
        __bf16* xh     = (__bf16*)d_ws;
        __bf16* h_ring = (__bf16*)((char*)d_ws + xh_bytes);
        int*    flags  = (int*)((char*)d_ws + xh_bytes + hring_bytes);
        xh_gemm<<<dim3(8192), dim3(256), 0, stream>>>(x, Wx, bx, xh);
        rnn_ring<true><<<dim3(256), dim3(64), 0, stream>>>(x, Wx, bx, Wh, xh, h_ring, flags);
        const __bf16* hT = h_ring + (size_t)((T_SZ - 1) & 3) * B_SZ * HDIM;
        logits_k<<<dim3(NCLS), dim3(256), 0, stream>>>(hT, Wy, by, (float*)d_out);
    } else {
        __bf16* h_ring = (__bf16*)d_ws;
        int*    flags  = (int*)((char*)d_ws + hring_bytes);
        rnn_ring<false><<<dim3(256), dim3(64), 0, stream>>>(x, Wx, bx, Wh, nullptr, h_ring, flags);
        const __bf16* hT = h_ring + (size_t)((T_SZ - 1) & 3) * B_SZ * HDIM;
        logits_k<<<dim3(NCLS), dim3(256), 0, stream>>>(hT, Wy, by, (float*)d_out);
    }
}

// Round 6
// 3752.397 us; speedup vs baseline: 2.0775x; 1.2921x over previous
//
#include <hip/hip_runtime.h>

// ---------------------------------------------------------------------------
// VanillaRNN on MI355X.  B=64, T=512, I=512, H=1024, C=1000.
//
// Phase 1: xh = x @ Wx^T + bx  (parallel MFMA GEMM, bf16 out, ws).
// Phase 2: ring kernel, 256 persistent waves (256 WGs x 64 thr, 1 wave/CU):
//   wave (g,w) owns batch rows g*16..+15, cols w*16..+15; Wh B-frags in VGPRs.
//   STAGGERED handoff: MFMA k-quarter grp (k = grp*256..+256) depends only on
//   producer waves grp*16..+16. Per step: poll(0),load(0) -> prefetch next
//   step's xh -> { poll(g+1),load(g+1) || mfma(g) } -> mfma(3) -> tanh ->
//   relaxed agent ATOMIC 2-B stores (sc1) -> s_waitcnt vmcnt(0) -> relaxed
//   flag store.  No wbl2/inv anywhere; consumer loads are relaxed agent
//   ATOMIC 8-B loads (R4/R5-proven coherent path).
//   h ring depth 4 (512 KB, cache-hot); flag>=t+2 before slot reuse => safe.
// Phase 3: fp32 logits GEMV.
// Flags poison 0xAAAAAAAA < 0 == "not ready" -> harness re-poison is init.
// No LDS in hot loops (R2/R3 failure was a TBAA-broken LDS repack).
// ---------------------------------------------------------------------------

typedef __bf16 bf16x8 __attribute__((ext_vector_type(8)));
typedef float  f32x4  __attribute__((ext_vector_type(4)));
typedef unsigned long long u64;

#define B_SZ 64
#define T_SZ 512
#define IDIM 512
#define HDIM 1024
#define NCLS 1000

__device__ __forceinline__ float tanh_fast(float v) {
    float e = __builtin_amdgcn_exp2f(v * 2.885390081777927f);
    return 1.f - 2.f * __builtin_amdgcn_rcpf(e + 1.f);
}

__device__ __forceinline__ bf16x8 cvt8(float4 a, float4 b) {
    bf16x8 v;
    v[0]=(__bf16)a.x; v[1]=(__bf16)a.y; v[2]=(__bf16)a.z; v[3]=(__bf16)a.w;
    v[4]=(__bf16)b.x; v[5]=(__bf16)b.y; v[6]=(__bf16)b.z; v[7]=(__bf16)b.w;
    return v;
}

// MFMA 16x16x32 bf16 layouts (m89/m91 verified):
//   A[m = lane&15][k = (lane>>4)*8 + j]
//   B[k = (lane>>4)*8 + j][n = lane&15]
//   D[row = (lane>>4)*4 + r][col = lane&15]

// ---------------------------------------------------------------------------
// Phase 1: xh GEMM.  grid 8192 x 256: tile 64 rows (m = b*T+t) x 64 cols.
// ---------------------------------------------------------------------------
__global__ __launch_bounds__(256)
void xh_gemm(const float* __restrict__ x,    // (32768, 512)
             const float* __restrict__ Wx,   // (1024, 512)
             const float* __restrict__ bx,   // (1024)
             __bf16* __restrict__ xh)        // (32768, 1024) bf16
{
    const int m0   = (blockIdx.x >> 4) * 64;
    const int n0   = (blockIdx.x & 15) * 64;
    const int wv   = threadIdx.x >> 6;
    const int lane = threadIdx.x & 63;
    const int l15  = lane & 15;
    const int quad = lane >> 4;
    const int nabs = n0 + wv * 16 + l15;

    bf16x8 wxf[16];
#pragma unroll
    for (int kk = 0; kk < 16; ++kk) {
        const float4* p = (const float4*)(Wx + (size_t)nabs * IDIM + kk * 32 + quad * 8);
        wxf[kk] = cvt8(p[0], p[1]);
    }
    const float bxv = bx[nabs];

    f32x4 acc[4] = {{0,0,0,0},{0,0,0,0},{0,0,0,0},{0,0,0,0}};
#pragma unroll
    for (int kk = 0; kk < 16; ++kk) {
#pragma unroll
        for (int rf = 0; rf < 4; ++rf) {
            const float4* p = (const float4*)(x + (size_t)(m0 + rf * 16 + l15) * IDIM + kk * 32 + quad * 8);
            bf16x8 a = cvt8(p[0], p[1]);
            acc[rf] = __builtin_amdgcn_mfma_f32_16x16x32_bf16(a, wxf[kk], acc[rf], 0, 0, 0);
        }
    }
#pragma unroll
    for (int rf = 0; rf < 4; ++rf)
#pragma unroll
        for (int r = 0; r < 4; ++r)
            xh[(size_t)(m0 + rf * 16 + quad * 4 + r) * HDIM + nabs] = (__bf16)(acc[rf][r] + bxv);
}

// ---------------------------------------------------------------------------
// Phase 2: the staggered ring.
// ---------------------------------------------------------------------------
#define AL64(p) __hip_atomic_load((p), __ATOMIC_RELAXED, __HIP_MEMORY_SCOPE_AGENT)

template <bool HAS_XH>
__global__ __launch_bounds__(64, 1)
void rnn_ring(const float* __restrict__ x,    // (64,512,512)
              const float* __restrict__ Wx,   // (1024,512)
              const float* __restrict__ bx,   // (1024)
              const float* __restrict__ Wh,   // (1024,1024)
              const __bf16* __restrict__ xh,  // (32768,1024) bf16 (HAS_XH)
              __bf16* h_ring,                 // (4,64,1024) bf16, ws
              int* flags)                     // (4*64) per-wave flags, ws
{
    const int g    = blockIdx.x >> 6;   // batch group 0..3 (rows g*16..+15)
    const int w    = blockIdx.x & 63;   // wave-in-group (cols w*16..+15)
    const int lane = threadIdx.x;
    const int l15  = lane & 15;
    const int quad = lane >> 4;
    const int nabs = w * 16 + l15;

    bf16x8 whf[32];
#pragma unroll
    for (int kk = 0; kk < 32; ++kk) {
        const float4* p = (const float4*)(Wh + (size_t)nabs * HDIM + kk * 32 + quad * 8);
        whf[kk] = cvt8(p[0], p[1]);
    }
    bf16x8 wxf[16];
    float bxv = 0.f;
    if (!HAS_XH) {
#pragma unroll
        for (int kk = 0; kk < 16; ++kk) {
            const float4* p = (const float4*)(Wx + (size_t)nabs * IDIM + kk * 32 + quad * 8);
            wxf[kk] = cvt8(p[0], p[1]);
        }
        bxv = bx[nabs];
    }

    const int* fl = flags + g * 64;
    const float* xrow = x + (size_t)(g * 16 + l15) * T_SZ * IDIM + quad * 8;

    // xh software pipeline: xhn holds step-t values at top of iteration t.
    float xhv[4], xhn[4];
    if (HAS_XH) {
#pragma unroll
        for (int r = 0; r < 4; ++r)
            xhn[r] = (float)xh[(size_t)(g * 16 + quad * 4 + r) * T_SZ * HDIM + nabs];
    }

    for (int t = 1; t <= T_SZ; ++t) {
        f32x4 acc0 = {0.f, 0.f, 0.f, 0.f};
        f32x4 acc1 = {0.f, 0.f, 0.f, 0.f};

        if (HAS_XH) {
#pragma unroll
            for (int r = 0; r < 4; ++r) xhv[r] = xhn[r];
        } else {
            const float4* xp = (const float4*)(xrow + (size_t)(t - 1) * IDIM);
#pragma unroll
            for (int kk = 0; kk < 16; kk += 2) {
                bf16x8 v0 = cvt8(xp[kk * 8], xp[kk * 8 + 1]);
                acc0 = __builtin_amdgcn_mfma_f32_16x16x32_bf16(v0, wxf[kk], acc0, 0, 0, 0);
                bf16x8 v1 = cvt8(xp[kk * 8 + 8], xp[kk * 8 + 9]);
                acc1 = __builtin_amdgcn_mfma_f32_16x16x32_bf16(v1, wxf[kk + 1], acc1, 0, 0, 0);
            }
#pragma unroll
            for (int r = 0; r < 4; ++r) xhv[r] = bxv;
        }

        const int tn = (t < T_SZ) ? t : (T_SZ - 1);   // next-step xh row index

        if (t > 1) {
            const u64* hq = (const u64*)(h_ring + ((size_t)((t - 2) & 3) * B_SZ + g * 16 + l15) * HDIM + quad * 8);
            u64 hb[4][16];

            // ---- grp 0: poll 16 flags, issue 16 loads ----------------------
            for (;;) { int f = AL64(fl + l15);      if (__all(f >= t - 1)) break; }
#pragma unroll
            for (int i = 0; i < 8; ++i) {
                hb[0][2*i]   = AL64(hq + i * 8);
                hb[0][2*i+1] = AL64(hq + i * 8 + 1);
            }
            // prefetch NEXT step's xh (retires under the MFMA phase)
            if (HAS_XH) {
#pragma unroll
                for (int r = 0; r < 4; ++r)
                    xhn[r] = (float)xh[((size_t)(g * 16 + quad * 4 + r) * T_SZ + tn) * HDIM + nabs];
            }

            // ---- grp 1..3: poll/load overlapped with mfma(grp-1) -----------
            for (;;) { int f = AL64(fl + 16 + l15); if (__all(f >= t - 1)) break; }
#pragma unroll
            for (int i = 0; i < 8; ++i) {
                hb[1][2*i]   = AL64(hq + (8 + i) * 8);
                hb[1][2*i+1] = AL64(hq + (8 + i) * 8 + 1);
            }
#pragma unroll
            for (int i = 0; i < 8; i += 2) {
                bf16x8 fa, fb;
                u64 qa[2] = { hb[0][2*i],   hb[0][2*i+1] };
                u64 qb[2] = { hb[0][2*i+2], hb[0][2*i+3] };
                __builtin_memcpy(&fa, qa, 16);
                __builtin_memcpy(&fb, qb, 16);
                acc0 = __builtin_amdgcn_mfma_f32_16x16x32_bf16(fa, whf[i],     acc0, 0, 0, 0);
                acc1 = __builtin_amdgcn_mfma_f32_16x16x32_bf16(fb, whf[i + 1], acc1, 0, 0, 0);
            }

            for (;;) { int f = AL64(fl + 32 + l15); if (__all(f >= t - 1)) break; }
#pragma unroll
            for (int i = 0; i < 8; ++i) {
                hb[2][2*i]   = AL64(hq + (16 + i) * 8);
                hb[2][2*i+1] = AL64(hq + (16 + i) * 8 + 1);
            }
#pragma unroll
            for (int i = 0; i < 8; i += 2) {
                bf16x8 fa, fb;
                u64 qa[2] = { hb[1][2*i],   hb[1][2*i+1] };
                u64 qb[2] = { hb[1][2*i+2], hb[1][2*i+3] };
                __builtin_memcpy(&fa, qa, 16);
                __builtin_memcpy(&fb, qb, 16);
                acc0 = __builtin_amdgcn_mfma_f32_16x16x32_bf16(fa, whf[8 + i],     acc0, 0, 0, 0);
                acc1 = __builtin_amdgcn_mfma_f32_16x16x32_bf16(fb, whf[8 + i + 1], acc1, 0, 0, 0);
            }

            for (;;) { int f = AL64(fl + 48 + l15); if (__all(f >= t - 1)) break; }
#pragma unroll
            for (int i = 0; i < 8; ++i) {
                hb[3][2*i]   = AL64(hq + (24 + i) * 8);
                hb[3][2*i+1] = AL64(hq + (24 + i) * 8 + 1);
            }
#pragma unroll
            for (int i = 0; i < 8; i += 2) {
                bf16x8 fa, fb;
                u64 qa[2] = { hb[2][2*i],   hb[2][2*i+1] };
                u64 qb[2] = { hb[2][2*i+2], hb[2][2*i+3] };
                __builtin_memcpy(&fa, qa, 16);
                __builtin_memcpy(&fb, qb, 16);
                acc0 = __builtin_amdgcn_mfma_f32_16x16x32_bf16(fa, whf[16 + i],     acc0, 0, 0, 0);
                acc1 = __builtin_amdgcn_mfma_f32_16x16x32_bf16(fb, whf[16 + i + 1], acc1, 0, 0, 0);
            }

#pragma unroll
            for (int i = 0; i < 8; i += 2) {
                bf16x8 fa, fb;
                u64 qa[2] = { hb[3][2*i],   hb[3][2*i+1] };
                u64 qb[2] = { hb[3][2*i+2], hb[3][2*i+3] };
                __builtin_memcpy(&fa, qa, 16);
                __builtin_memcpy(&fb, qb, 16);
                acc0 = __builtin_amdgcn_mfma_f32_16x16x32_bf16(fa, whf[24 + i],     acc0, 0, 0, 0);
                acc1 = __builtin_amdgcn_mfma_f32_16x16x32_bf16(fb, whf[24 + i + 1], acc1, 0, 0, 0);
            }
        } else if (HAS_XH) {
#pragma unroll
            for (int r = 0; r < 4; ++r)
                xhn[r] = (float)xh[((size_t)(g * 16 + quad * 4 + r) * T_SZ + tn) * HDIM + nabs];
        }

        // ---- epilogue: tanh + relaxed agent ATOMIC 2-B stores (sc1) --------
        {
            __bf16* hout = h_ring + (size_t)((t - 1) & 3) * B_SZ * HDIM;
#pragma unroll
            for (int r = 0; r < 4; ++r) {
                float a = acc0[r] + acc1[r] + xhv[r];
                __bf16 hv = (__bf16)tanh_fast(a);
                unsigned short bits = __builtin_bit_cast(unsigned short, hv);
                unsigned short* dst = (unsigned short*)
                    (hout + (size_t)(g * 16 + quad * 4 + r) * HDIM + nabs);
                __hip_atomic_store(dst, bits, __ATOMIC_RELAXED, __HIP_MEMORY_SCOPE_AGENT);
            }
        }

        // ---- publish: drain stores, then relaxed flag (no wbl2) ------------
        __asm__ __volatile__("s_waitcnt vmcnt(0)" ::: "memory");
        if (lane == 0)
            __hip_atomic_store(flags + g * 64 + w, t,
                               __ATOMIC_RELAXED, __HIP_MEMORY_SCOPE_AGENT);
    }
}

// ---------------------------------------------------------------------------
// Phase 3: logits[b][j] = sum_k hT[b][k] * Wy[j][k] + by[j]   (fp32)
// ---------------------------------------------------------------------------
__global__ __launch_bounds__(256)
void logits_k(const __bf16* __restrict__ hT,   // (64,1024) bf16
              const float* __restrict__ Wy,    // (1000,1024)
              const float* __restrict__ by,    // (1000)
              float* __restrict__ out)         // (64,1000)
{
    const int j = blockIdx.x;
    const int q = threadIdx.x & 3;
    const int b = threadIdx.x >> 2;
    const float*  wr = Wy + (size_t)j * HDIM + q * 256;
    const __bf16* hr = hT + (size_t)b * HDIM + q * 256;
    float s = 0.f;
#pragma unroll 8
    for (int kk = 0; kk < 32; ++kk) {
        bf16x8 h8 = *(const bf16x8*)(hr + kk * 8);
        float4 w0 = *(const float4*)(wr + kk * 8);
        float4 w1 = *(const float4*)(wr + kk * 8 + 4);
        s += w0.x * (float)h8[0] + w0.y * (float)h8[1] + w0.z * (float)h8[2] + w0.w * (float)h8[3]
           + w1.x * (float)h8[4] + w1.y * (float)h8[5] + w1.z * (float)h8[6] + w1.w * (float)h8[7];
    }
    s += __shfl_xor(s, 1);
    s += __shfl_xor(s, 2);
    if (q == 0) out[b * NCLS + j] = s + by[j];
}

extern "C" void kernel_launch(void* const* d_in, const int* in_sizes, int n_in,
                              void* d_out, int out_size, void* d_ws, size_t ws_size,
                              hipStream_t stream) {
    (void)in_sizes; (void)n_in; (void)out_size;
    const float* x  = (const float*)d_in[0];
    const float* Wx = (const float*)d_in[1];
    const float* bx = (const float*)d_in[2];
    const float* Wh = (const float*)d_in[3];
    const float* Wy = (const float*)d_in[4];
    const float* by = (const float*)d_in[5];

    const size_t xh_bytes    = (size_t)B_SZ * T_SZ * HDIM * 2;   // 67.1 MB
    const size_t hring_bytes = (size_t)4 * B_SZ * HDIM * 2;      // 512 KB
    const bool   big_ws      = ws_size >= xh_bytes + hring_bytes + 4096;

    if (big_ws) {
        __bf16* xh     = (__bf16*)d_ws;
        __bf16* h_ring = (__bf16*)((char*)d_ws + xh_bytes);
        int*    flags  = (int*)((char*)d_ws + xh_bytes + hring_bytes);
        xh_gemm<<<dim3(8192), dim3(256), 0, stream>>>(x, Wx, bx, xh);
        rnn_ring<true><<<dim3(256), dim3(64), 0, stream>>>(x, Wx, bx, Wh, xh, h_ring, flags);
        const __bf16* hT = h_ring + (size_t)((T_SZ - 1) & 3) * B_SZ * HDIM;
        logits_k<<<dim3(NCLS), dim3(256), 0, stream>>>(hT, Wy, by, (float*)d_out);
    } else {
        __bf16* h_ring = (__bf16*)d_ws;
        int*    flags  = (int*)((char*)d_ws + hring_bytes);
        rnn_ring<false><<<dim3(256), dim3(64), 0, stream>>>(x, Wx, bx, Wh, nullptr, h_ring, flags);
        const __bf16* hT = h_ring + (size_t)((T_SZ - 1) & 3) * B_SZ * HDIM;
        logits_k<<<dim3(NCLS), dim3(256), 0, stream>>>(hT, Wy, by, (float*)d_out);
    }
}

// Round 7
// 3750.659 us; speedup vs baseline: 2.0784x; 1.0005x over previous
//
#include <hip/hip_runtime.h>

// ---------------------------------------------------------------------------
// VanillaRNN on MI355X.  B=64, T=512, I=512, H=1024, C=1000.
//
// Phase 1: xh = x @ Wx^T + bx  (parallel MFMA GEMM) written TRANSPOSED as
//          xh_T[n][m] (n=hidden col, m=b*512+t), bf16, via LDS transpose with
//          coalesced 16-B stores.
// Phase 2: ring kernel, 256 persistent waves (256 WGs x 64 thr, 1 wave/CU):
//   wave (g,w) owns batch rows g*16..+15, cols w*16..+15; Wh B-frags in VGPRs.
//   Staggered handoff: MFMA k-quarter grp depends only on producer waves
//   grp*16..+16 (16 flags each), polls overlapped with loads/MFMAs.
//   xh: bulk 16-step prefetch (8 x 16-B contiguous loads -> LDS) every 16
//   steps; per-step 4 x ds_read_u16 (no per-step HBM RT in the chain).
//   Epilogue: tanh -> ushort-LDS transpose (memcpy reads, TBAA-safe) ->
//   ONE coalesced 8-B relaxed agent ATOMIC store per lane (sc1 -> L3) ->
//   s_waitcnt vmcnt(0) -> relaxed flag store. No wbl2/inv anywhere.
//   h ring depth 4 (512 KB, cache-hot); flag>=t+2 before slot reuse => safe.
// Phase 3: fp32 logits GEMV.
// Flags poison 0xAAAAAAAA < 0 == "not ready" -> harness re-poison is init.
// ---------------------------------------------------------------------------

typedef __bf16 bf16x8 __attribute__((ext_vector_type(8)));
typedef float  f32x4  __attribute__((ext_vector_type(4)));
typedef unsigned long long u64;
typedef unsigned short u16;

#define B_SZ 64
#define T_SZ 512
#define IDIM 512
#define HDIM 1024
#define NCLS 1000
#define MTOT (B_SZ * T_SZ)   // 32768

__device__ __forceinline__ float tanh_fast(float v) {
    float e = __builtin_amdgcn_exp2f(v * 2.885390081777927f);
    return 1.f - 2.f * __builtin_amdgcn_rcpf(e + 1.f);
}

__device__ __forceinline__ bf16x8 cvt8(float4 a, float4 b) {
    bf16x8 v;
    v[0]=(__bf16)a.x; v[1]=(__bf16)a.y; v[2]=(__bf16)a.z; v[3]=(__bf16)a.w;
    v[4]=(__bf16)b.x; v[5]=(__bf16)b.y; v[6]=(__bf16)b.z; v[7]=(__bf16)b.w;
    return v;
}

// MFMA 16x16x32 bf16 layouts (m89/m91 verified):
//   A[m = lane&15][k = (lane>>4)*8 + j]
//   B[k = (lane>>4)*8 + j][n = lane&15]
//   D[row = (lane>>4)*4 + r][col = lane&15]

// ---------------------------------------------------------------------------
// Phase 1: xh GEMM with transposed output.
// grid 8192 x 256: tile 64 m-rows x 64 n-cols.  xh_T[n][m].
// ---------------------------------------------------------------------------
__global__ __launch_bounds__(256)
void xh_gemm(const float* __restrict__ x,    // (32768, 512)
             const float* __restrict__ Wx,   // (1024, 512)
             const float* __restrict__ bx,   // (1024)
             __bf16* __restrict__ xh_T)      // (1024, 32768) bf16
{
    __shared__ __attribute__((aligned(16))) u16 tile_sh[64 * 72];  // [n][m], stride 72

    const int m0   = (blockIdx.x >> 4) * 64;
    const int n0   = (blockIdx.x & 15) * 64;
    const int wv   = threadIdx.x >> 6;
    const int lane = threadIdx.x & 63;
    const int l15  = lane & 15;
    const int quad = lane >> 4;
    const int nabs = n0 + wv * 16 + l15;

    bf16x8 wxf[16];
#pragma unroll
    for (int kk = 0; kk < 16; ++kk) {
        const float4* p = (const float4*)(Wx + (size_t)nabs * IDIM + kk * 32 + quad * 8);
        wxf[kk] = cvt8(p[0], p[1]);
    }
    const float bxv = bx[nabs];

    f32x4 acc[4] = {{0,0,0,0},{0,0,0,0},{0,0,0,0},{0,0,0,0}};
#pragma unroll
    for (int kk = 0; kk < 16; ++kk) {
#pragma unroll
        for (int rf = 0; rf < 4; ++rf) {
            const float4* p = (const float4*)(x + (size_t)(m0 + rf * 16 + l15) * IDIM + kk * 32 + quad * 8);
            bf16x8 a = cvt8(p[0], p[1]);
            acc[rf] = __builtin_amdgcn_mfma_f32_16x16x32_bf16(a, wxf[kk], acc[rf], 0, 0, 0);
        }
    }
    // D-frags -> LDS [n_local][m_local]
#pragma unroll
    for (int rf = 0; rf < 4; ++rf)
#pragma unroll
        for (int r = 0; r < 4; ++r) {
            __bf16 hv = (__bf16)(acc[rf][r] + bxv);
            tile_sh[(wv * 16 + l15) * 72 + rf * 16 + quad * 4 + r] =
                __builtin_bit_cast(u16, hv);
        }
    __syncthreads();
    // coalesced transposed store: 8 lanes x 16 B per n-row
#pragma unroll
    for (int rep = 0; rep < 2; ++rep) {
        const int nl  = (threadIdx.x >> 3) + rep * 32;
        const int mch = threadIdx.x & 7;
        uint4 v;
        __builtin_memcpy(&v, &tile_sh[nl * 72 + mch * 8], 16);
        *(uint4*)(xh_T + (size_t)(n0 + nl) * MTOT + m0 + mch * 8) = v;
    }
}

// ---------------------------------------------------------------------------
// Phase 2: the staggered ring.
// ---------------------------------------------------------------------------
#define AL64(p) __hip_atomic_load((p), __ATOMIC_RELAXED, __HIP_MEMORY_SCOPE_AGENT)

template <bool HAS_XH>
__global__ __launch_bounds__(64, 1)
void rnn_ring(const float* __restrict__ x,    // (64,512,512)
              const float* __restrict__ Wx,   // (1024,512)
              const float* __restrict__ bx,   // (1024)
              const float* __restrict__ Wh,   // (1024,1024)
              const __bf16* __restrict__ xh,  // (1024,32768) bf16 xh_T (HAS_XH)
              __bf16* h_ring,                 // (4,64,1024) bf16, ws
              int* flags)                     // (4*64) per-wave flags, ws
{
    // per-lane xh stash: [lane][r][p]  (stride 68 ushorts = 136 B -> lane,
    // lane+16 share a bank: 2-way, free). 8704 B.
    __shared__ __attribute__((aligned(16))) u16 xh_sh[64 * 68];
    // epilogue transpose: [row][col], stride 20 ushorts (8-B aligned rows). 640 B.
    __shared__ __attribute__((aligned(16))) u16 ep_sh[16 * 20];

    const int g    = blockIdx.x >> 6;   // batch group 0..3 (rows g*16..+15)
    const int w    = blockIdx.x & 63;   // wave-in-group (cols w*16..+15)
    const int lane = threadIdx.x;
    const int l15  = lane & 15;
    const int quad = lane >> 4;
    const int nabs = w * 16 + l15;

    bf16x8 whf[32];
#pragma unroll
    for (int kk = 0; kk < 32; ++kk) {
        const float4* p = (const float4*)(Wh + (size_t)nabs * HDIM + kk * 32 + quad * 8);
        whf[kk] = cvt8(p[0], p[1]);
    }
    bf16x8 wxf[16];
    float bxv = 0.f;
    if (!HAS_XH) {
#pragma unroll
        for (int kk = 0; kk < 16; ++kk) {
            const float4* p = (const float4*)(Wx + (size_t)nabs * IDIM + kk * 32 + quad * 8);
            wxf[kk] = cvt8(p[0], p[1]);
        }
        bxv = bx[nabs];
    }

    const int* fl = flags + g * 64;
    const float* xrow = x + (size_t)(g * 16 + l15) * T_SZ * IDIM + quad * 8;
    const int prow = lane >> 2;          // epilogue read row
    const int pcg  = lane & 3;           // epilogue read col-group

    for (int t = 1; t <= T_SZ; ++t) {
        f32x4 acc0 = {0.f, 0.f, 0.f, 0.f};
        f32x4 acc1 = {0.f, 0.f, 0.f, 0.f};
        float xhv[4];

        if (HAS_XH) {
            // ---- bulk 16-step xh prefetch (amortized HBM RT) ---------------
            if (((t - 1) & 15) == 0) {
                const int tb = t - 1;
#pragma unroll
                for (int r = 0; r < 4; ++r) {
                    const int row = g * 16 + quad * 4 + r;
                    const uint4* xp = (const uint4*)(xh + (size_t)nabs * MTOT + row * T_SZ + tb);
                    uint4 v0 = xp[0], v1 = xp[1];
                    __builtin_memcpy(&xh_sh[lane * 68 + r * 16],     &v0, 16);
                    __builtin_memcpy(&xh_sh[lane * 68 + r * 16 + 8], &v1, 16);
                }
            }
            const int p = (t - 1) & 15;
#pragma unroll
            for (int r = 0; r < 4; ++r) {
                u16 us = xh_sh[lane * 68 + r * 16 + p];
                xhv[r] = (float)__builtin_bit_cast(__bf16, us);
            }
        } else {
            const float4* xp = (const float4*)(xrow + (size_t)(t - 1) * IDIM);
#pragma unroll
            for (int kk = 0; kk < 16; kk += 2) {
                bf16x8 v0 = cvt8(xp[kk * 8], xp[kk * 8 + 1]);
                acc0 = __builtin_amdgcn_mfma_f32_16x16x32_bf16(v0, wxf[kk], acc0, 0, 0, 0);
                bf16x8 v1 = cvt8(xp[kk * 8 + 8], xp[kk * 8 + 9]);
                acc1 = __builtin_amdgcn_mfma_f32_16x16x32_bf16(v1, wxf[kk + 1], acc1, 0, 0, 0);
            }
#pragma unroll
            for (int r = 0; r < 4; ++r) xhv[r] = bxv;
        }

        if (t > 1) {
            const u64* hq = (const u64*)(h_ring + ((size_t)((t - 2) & 3) * B_SZ + g * 16 + l15) * HDIM + quad * 8);
            u64 hb[4][16];

            // ---- grp 0: poll 16 flags, issue 16 loads ----------------------
            for (;;) { int f = AL64(fl + l15);      if (__all(f >= t - 1)) break; }
#pragma unroll
            for (int i = 0; i < 8; ++i) {
                hb[0][2*i]   = AL64(hq + i * 8);
                hb[0][2*i+1] = AL64(hq + i * 8 + 1);
            }

            // ---- grp 1..3: poll/load overlapped with mfma(grp-1) -----------
            for (;;) { int f = AL64(fl + 16 + l15); if (__all(f >= t - 1)) break; }
#pragma unroll
            for (int i = 0; i < 8; ++i) {
                hb[1][2*i]   = AL64(hq + (8 + i) * 8);
                hb[1][2*i+1] = AL64(hq + (8 + i) * 8 + 1);
            }
#pragma unroll
            for (int i = 0; i < 8; i += 2) {
                bf16x8 fa, fb;
                u64 qa[2] = { hb[0][2*i],   hb[0][2*i+1] };
                u64 qb[2] = { hb[0][2*i+2], hb[0][2*i+3] };
                __builtin_memcpy(&fa, qa, 16);
                __builtin_memcpy(&fb, qb, 16);
                acc0 = __builtin_amdgcn_mfma_f32_16x16x32_bf16(fa, whf[i],     acc0, 0, 0, 0);
                acc1 = __builtin_amdgcn_mfma_f32_16x16x32_bf16(fb, whf[i + 1], acc1, 0, 0, 0);
            }

            for (;;) { int f = AL64(fl + 32 + l15); if (__all(f >= t - 1)) break; }
#pragma unroll
            for (int i = 0; i < 8; ++i) {
                hb[2][2*i]   = AL64(hq + (16 + i) * 8);
                hb[2][2*i+1] = AL64(hq + (16 + i) * 8 + 1);
            }
#pragma unroll
            for (int i = 0; i < 8; i += 2) {
                bf16x8 fa, fb;
                u64 qa[2] = { hb[1][2*i],   hb[1][2*i+1] };
                u64 qb[2] = { hb[1][2*i+2], hb[1][2*i+3] };
                __builtin_memcpy(&fa, qa, 16);
                __builtin_memcpy(&fb, qb, 16);
                acc0 = __builtin_amdgcn_mfma_f32_16x16x32_bf16(fa, whf[8 + i],     acc0, 0, 0, 0);
                acc1 = __builtin_amdgcn_mfma_f32_16x16x32_bf16(fb, whf[8 + i + 1], acc1, 0, 0, 0);
            }

            for (;;) { int f = AL64(fl + 48 + l15); if (__all(f >= t - 1)) break; }
#pragma unroll
            for (int i = 0; i < 8; ++i) {
                hb[3][2*i]   = AL64(hq + (24 + i) * 8);
                hb[3][2*i+1] = AL64(hq + (24 + i) * 8 + 1);
            }
#pragma unroll
            for (int i = 0; i < 8; i += 2) {
                bf16x8 fa, fb;
                u64 qa[2] = { hb[2][2*i],   hb[2][2*i+1] };
                u64 qb[2] = { hb[2][2*i+2], hb[2][2*i+3] };
                __builtin_memcpy(&fa, qa, 16);
                __builtin_memcpy(&fb, qb, 16);
                acc0 = __builtin_amdgcn_mfma_f32_16x16x32_bf16(fa, whf[16 + i],     acc0, 0, 0, 0);
                acc1 = __builtin_amdgcn_mfma_f32_16x16x32_bf16(fb, whf[16 + i + 1], acc1, 0, 0, 0);
            }

#pragma unroll
            for (int i = 0; i < 8; i += 2) {
                bf16x8 fa, fb;
                u64 qa[2] = { hb[3][2*i],   hb[3][2*i+1] };
                u64 qb[2] = { hb[3][2*i+2], hb[3][2*i+3] };
                __builtin_memcpy(&fa, qa, 16);
                __builtin_memcpy(&fb, qb, 16);
                acc0 = __builtin_amdgcn_mfma_f32_16x16x32_bf16(fa, whf[24 + i],     acc0, 0, 0, 0);
                acc1 = __builtin_amdgcn_mfma_f32_16x16x32_bf16(fb, whf[24 + i + 1], acc1, 0, 0, 0);
            }
        }

        // ---- epilogue: tanh -> ushort LDS transpose -> ONE 8-B sc1 store ---
#pragma unroll
        for (int r = 0; r < 4; ++r) {
            float a = acc0[r] + acc1[r] + xhv[r];
            __bf16 hv = (__bf16)tanh_fast(a);
            ep_sh[(quad * 4 + r) * 20 + l15] = __builtin_bit_cast(u16, hv);
        }
        u64 pv;
        __builtin_memcpy(&pv, &ep_sh[prow * 20 + pcg * 4], 8);   // same-wave, alias-visible
        u64* dst = (u64*)(h_ring + (size_t)((t - 1) & 3) * B_SZ * HDIM
                          + (size_t)(g * 16 + prow) * HDIM + w * 16 + pcg * 4);
        __hip_atomic_store(dst, pv, __ATOMIC_RELAXED, __HIP_MEMORY_SCOPE_AGENT);

        // ---- publish: drain the store, then relaxed flag (no wbl2) ---------
        __asm__ __volatile__("s_waitcnt vmcnt(0)" ::: "memory");
        if (lane == 0)
            __hip_atomic_store(flags + g * 64 + w, t,
                               __ATOMIC_RELAXED, __HIP_MEMORY_SCOPE_AGENT);
    }
}

// ---------------------------------------------------------------------------
// Phase 3: logits[b][j] = sum_k hT[b][k] * Wy[j][k] + by[j]   (fp32)
// ---------------------------------------------------------------------------
__global__ __launch_bounds__(256)
void logits_k(const __bf16* __restrict__ hT,   // (64,1024) bf16
              const float* __restrict__ Wy,    // (1000,1024)
              const float* __restrict__ by,    // (1000)
              float* __restrict__ out)         // (64,1000)
{
    const int j = blockIdx.x;
    const int q = threadIdx.x & 3;
    const int b = threadIdx.x >> 2;
    const float*  wr = Wy + (size_t)j * HDIM + q * 256;
    const __bf16* hr = hT + (size_t)b * HDIM + q * 256;
    float s = 0.f;
#pragma unroll 8
    for (int kk = 0; kk < 32; ++kk) {
        bf16x8 h8 = *(const bf16x8*)(hr + kk * 8);
        float4 w0 = *(const float4*)(wr + kk * 8);
        float4 w1 = *(const float4*)(wr + kk * 8 + 4);
        s += w0.x * (float)h8[0] + w0.y * (float)h8[1] + w0.z * (float)h8[2] + w0.w * (float)h8[3]
           + w1.x * (float)h8[4] + w1.y * (float)h8[5] + w1.z * (float)h8[6] + w1.w * (float)h8[7];
    }
    s += __shfl_xor(s, 1);
    s += __shfl_xor(s, 2);
    if (q == 0) out[b * NCLS + j] = s + by[j];
}

extern "C" void kernel_launch(void* const* d_in, const int* in_sizes, int n_in,
                              void* d_out, int out_size, void* d_ws, size_t ws_size,
                              hipStream_t stream) {
    (void)in_sizes; (void)n_in; (void)out_size;
    const float* x  = (const float*)d_in[0];
    const float* Wx = (const float*)d_in[1];
    const float* bx = (const float*)d_in[2];
    const float* Wh = (const float*)d_in[3];
    const float* Wy = (const float*)d_in[4];
    const float* by = (const float*)d_in[5];

    const size_t xh_bytes    = (size_t)MTOT * HDIM * 2;          // 67.1 MB
    const size_t hring_bytes = (size_t)4 * B_SZ * HDIM * 2;      // 512 KB
    const bool   big_ws      = ws_size >= xh_bytes + hring_bytes + 4096;

    if (big_ws) {
        __bf16* xh_T   = (__bf16*)d_ws;
        __bf16* h_ring = (__bf16*)((char*)d_ws + xh_bytes);
        int*    flags  = (int*)((char*)d_ws + xh_bytes + hring_bytes);
        xh_gemm<<<dim3(8192), dim3(256), 0, stream>>>(x, Wx, bx, xh_T);
        rnn_ring<true><<<dim3(256), dim3(64), 0, stream>>>(x, Wx, bx, Wh, xh_T, h_ring, flags);
        const __bf16* hT = h_ring + (size_t)((T_SZ - 1) & 3) * B_SZ * HDIM;
        logits_k<<<dim3(NCLS), dim3(256), 0, stream>>>(hT, Wy, by, (float*)d_out);
    } else {
        __bf16* h_ring = (__bf16*)d_ws;
        int*    flags  = (int*)((char*)d_ws + hring_bytes);
        rnn_ring<false><<<dim3(256), dim3(64), 0, stream>>>(x, Wx, bx, Wh, nullptr, h_ring, flags);
        const __bf16* hT = h_ring + (size_t)((T_SZ - 1) & 3) * B_SZ * HDIM;
        logits_k<<<dim3(NCLS), dim3(256), 0, stream>>>(hT, Wy, by, (float*)d_out);
    }
}